// Round 20
// baseline (459.460 us; speedup 1.0000x reference)
//
#include <hip/hip_runtime.h>
#include <cstdint>
#include <cstddef>

typedef unsigned short u16;
typedef __attribute__((ext_vector_type(4))) float f32x4;
typedef __attribute__((ext_vector_type(8))) short s16x8;

#define D_EMB 1024
#define NSEQ 1024
#define NB 8
#define NH 16
#define HS 64
#define DFF 4096
#define MTOT (NB*NSEQ)

__device__ __forceinline__ u16 f2bf(float f){
  unsigned u = __float_as_uint(f);
  u += 0x7FFFu + ((u >> 16) & 1u);     // round-to-nearest-even
  return (u16)(u >> 16);
}
// truncating convert (P-tile only: P>0, <=1 ULP bias cancels in softmax ratio)
__device__ __forceinline__ u16 bft(float f){ return (u16)(__float_as_uint(f) >> 16); }
__device__ __forceinline__ float bf2f(u16 v){ return __uint_as_float(((unsigned)v) << 16); }

__device__ __forceinline__ void gload_lds16(const void* g, void* l){
  __builtin_amdgcn_global_load_lds((const __attribute__((address_space(1))) void*)g,
                                   (__attribute__((address_space(3))) void*)l, 16, 0, 0);
}

#define WAITV(n) asm volatile("s_waitcnt vmcnt(" #n ")" ::: "memory")

// ---------------- tiled transpose + fp32->bf16 convert ----------------
__global__ void transpose_cvt(const float* __restrict__ in, u16* __restrict__ out,
                              int R, int C, size_t inStride, size_t outStride){
  __shared__ float t[32][33];
  const float* ip = in + (size_t)blockIdx.z * inStride;
  u16* op = out + (size_t)blockIdx.z * outStride;
  int c0 = blockIdx.x * 32, r0 = blockIdx.y * 32;
  int tx = threadIdx.x, ty = threadIdx.y;
#pragma unroll
  for (int j = 0; j < 32; j += 8)
    t[ty + j][tx] = ip[(size_t)(r0 + ty + j) * C + (c0 + tx)];
  __syncthreads();
#pragma unroll
  for (int j = 0; j < 32; j += 8)
    op[(size_t)(c0 + ty + j) * R + (r0 + tx)] = f2bf(t[tx][ty + j]);
}

// merged QKV weight transpose: z in [0,48), weight = z/16, head = z%16
__global__ void transpose_cvt_qkv(const float* __restrict__ Wq,
                                  const float* __restrict__ Wk,
                                  const float* __restrict__ Wv,
                                  u16* __restrict__ out){
  __shared__ float t[32][33];
  const int z = blockIdx.z, wsel = z >> 4, h = z & 15;
  const float* w = (wsel == 0) ? Wq : (wsel == 1) ? Wk : Wv;
  const float* ip = w + (size_t)h * D_EMB * HS;
  u16* op = out + (size_t)wsel * D_EMB * D_EMB + (size_t)h * HS * D_EMB;
  int c0 = blockIdx.x * 32, r0 = blockIdx.y * 32;
  int tx = threadIdx.x, ty = threadIdx.y;
#pragma unroll
  for (int j = 0; j < 32; j += 8)
    t[ty + j][tx] = ip[(size_t)(r0 + ty + j) * HS + (c0 + tx)];
  __syncthreads();
#pragma unroll
  for (int j = 0; j < 32; j += 8)
    op[(size_t)(c0 + ty + j) * D_EMB + (r0 + tx)] = f2bf(t[tx][ty + j]);
}

// ---------------- LayerNorm (fp32 OR bf16 in, bf16 out) ----------------
template<bool BF16IN>
__global__ __launch_bounds__(256) void ln_kernel(const void* __restrict__ xin,
    const float* __restrict__ g, const float* __restrict__ bb, u16* __restrict__ out){
  int row = blockIdx.x;
  int c = threadIdx.x * 4;
  float v0, v1, v2, v3;
  if (BF16IN){
    const u16* xr = (const u16*)xin + (size_t)row * D_EMB;
    ushort4 u = *(const ushort4*)(xr + c);
    v0 = bf2f(u.x); v1 = bf2f(u.y); v2 = bf2f(u.z); v3 = bf2f(u.w);
  } else {
    const float* xr = (const float*)xin + (size_t)row * D_EMB;
    f32x4 v = *(const f32x4*)(xr + c);
    v0 = v[0]; v1 = v[1]; v2 = v[2]; v3 = v[3];
  }
  float s1 = v0 + v1 + v2 + v3;
  float s2 = v0*v0 + v1*v1 + v2*v2 + v3*v3;
#pragma unroll
  for (int m = 32; m > 0; m >>= 1){ s1 += __shfl_xor(s1, m); s2 += __shfl_xor(s2, m); }
  __shared__ float ps1[4], ps2[4];
  int w = threadIdx.x >> 6;
  if ((threadIdx.x & 63) == 0){ ps1[w] = s1; ps2[w] = s2; }
  __syncthreads();
  s1 = ps1[0] + ps1[1] + ps1[2] + ps1[3];
  s2 = ps2[0] + ps2[1] + ps2[2] + ps2[3];
  float mu = s1 * (1.f / D_EMB);
  float var = s2 * (1.f / D_EMB) - mu * mu;
  float rs = rsqrtf(var + 1e-5f);
  ushort4 o;
  o.x = f2bf((v0-mu)*rs*g[c+0] + bb[c+0]);
  o.y = f2bf((v1-mu)*rs*g[c+1] + bb[c+1]);
  o.z = f2bf((v2-mu)*rs*g[c+2] + bb[c+2]);
  o.w = f2bf((v3-mu)*rs*g[c+3] + bb[c+3]);
  *(ushort4*)(out + (size_t)row * D_EMB + c) = o;
}

// ======== 2-phase GEMM template, A-panel-major block order (r15/r19 best) ========
// MODE 0: QKV (Q scaled 0.125*log2e); MODE 2: ff1 leakyrelu bf16.
template<int MODE, int BMT, int BNT, int NTHR>
__global__ __launch_bounds__(NTHR) void gemm2ph(
    const u16* __restrict__ A, const u16* __restrict__ Bt,
    int M, int N, int K,
    const float* __restrict__ bias0, const float* __restrict__ bias1,
    const float* __restrict__ bias2, const void* __restrict__ resid,
    void* __restrict__ o0, void* __restrict__ o1, void* __restrict__ o2)
{
  constexpr int NWAVE = NTHR/64;
  constexpr int WCN = BNT/64, WRN = NWAVE/WCN;
  constexpr int WROWS = BMT/WRN;                 // rows per wave
  constexpr int RF = WROWS/16;                   // row fragments per wave
  static_assert(RF*16*WRN == BMT, "wave tiling must cover BMT");
  constexpr int RPP = NTHR/4;                    // rows staged per pass
  constexpr int ALD = (BMT*32)/(NTHR*8);         // 16B loads/thread for A
  constexpr int BLD = (BNT*32)/(NTHR*8);
  __shared__ alignas(16) u16 Al[2][BMT*32];
  __shared__ alignas(16) u16 Bl[2][BNT*32];

  const int tid = threadIdx.x;
  const int wid = tid>>6, lane = tid&63, lr = lane&15, lg = lane>>4;
  const int wr = wid/WCN, wc = wid%WCN;

  // XCD swizzle (all grids divisible by 8) + A-panel-major (n inner)
  const int gx = gridDim.x;
  const int gy = gridDim.y;
  const int nwg = gx * gy;
  const int bid = blockIdx.x + blockIdx.y*gx;
  const int wg = (bid&7)*(nwg>>3) + (bid>>3);
  const int m0 = (wg / gy) * BMT;    // consecutive wg share m0 (A panel)
  const int n0 = (wg % gy) * BNT;

  const int srow = tid>>2;                                   // staging row
  const int scs = (((tid&3) - ((srow>>1)&3)) & 3) * 8;       // inv-swizzled src chunk

  auto stage = [&](int buf, int kt){
    const u16* asrc = A + (size_t)(m0 + srow)*K + kt*32 + scs;
#pragma unroll
    for (int r = 0; r < ALD; ++r)
      gload_lds16(asrc + (size_t)(r*RPP)*K, &Al[buf][r*(NTHR*8) + tid*8]);
    const u16* bsrc = Bt + (size_t)(n0 + srow)*K + kt*32 + scs;
#pragma unroll
    for (int r = 0; r < BLD; ++r)
      gload_lds16(bsrc + (size_t)(r*RPP)*K, &Bl[buf][r*(NTHR*8) + tid*8]);
  };

  f32x4 acc[RF][4];
#pragma unroll
  for (int i = 0; i < RF; i++)
#pragma unroll
    for (int j = 0; j < 4; j++) acc[i][j] = {0.f,0.f,0.f,0.f};

  const int nk = K/32;
  stage(0, 0);
  for (int kt = 0; kt < nk; ++kt){
    __syncthreads();                   // drains vmcnt: stage(kt) visible
    if (kt + 1 < nk) stage((kt+1)&1, kt+1);
    const int buf = kt & 1;
    s16x8 af[RF], bf[4];
#pragma unroll
    for (int i = 0; i < RF; i++){
      const int ar = wr*WROWS + i*16 + lr;
      af[i] = *(const s16x8*)&Al[buf][ar*32 + (((lg + (ar>>1)) & 3)<<3)];
    }
#pragma unroll
    for (int j = 0; j < 4; j++){
      const int br = wc*64 + j*16 + lr;
      bf[j] = *(const s16x8*)&Bl[buf][br*32 + (((lg + (br>>1)) & 3)<<3)];
    }
#pragma unroll
    for (int i = 0; i < RF; i++)
#pragma unroll
      for (int j = 0; j < 4; j++)
        acc[i][j] = __builtin_amdgcn_mfma_f32_16x16x32_bf16(af[i], bf[j], acc[i][j], 0, 0, 0);
  }

  // epilogue: lane holds C[row=lg*4+i][col=lr] per 16x16 fragment
#pragma unroll
  for (int fm = 0; fm < RF; fm++){
    const int gmb = m0 + wr*WROWS + fm*16 + lg*4;
#pragma unroll
    for (int fn = 0; fn < 4; fn++){
      const int gn = n0 + wc*64 + fn*16 + lr;
#pragma unroll
      for (int i = 0; i < 4; i++){
        const int gm = gmb + i;
        float v = acc[fm][fn][i];
        if (MODE == 0){
          const int cls = gn >> 10, nn = gn & 1023;
          if (cls == 0)      ((u16*)o0)[(size_t)gm * D_EMB + nn] = f2bf((v + bias0[nn]) * 0.18033688f); // 0.125*log2e
          else if (cls == 1) ((u16*)o1)[(size_t)gm * D_EMB + nn] = f2bf(v + bias1[nn]);
          else {
            const int hh = nn >> 6, ss = nn & 63, bb = gm >> 10, tt = gm & 1023;
            ((u16*)o2)[(((size_t)(bb * NH + hh)) * HS + ss) * NSEQ + tt] = f2bf(v + bias2[nn]);
          }
        } else if (MODE == 1){
          ((u16*)o0)[(size_t)gm * N + gn] =
              f2bf(((const float*)resid)[(size_t)gm * N + gn] + v + bias0[gn]);
        } else if (MODE == 3){
          ((float*)o0)[(size_t)gm * N + gn] =
              bf2f(((const u16*)resid)[(size_t)gm * N + gn]) + v + bias0[gn];
        } else {
          float y = v + bias0[gn];
          y = y > 0.f ? y : 0.01f * y;
          ((u16*)o0)[(size_t)gm * N + gn] = f2bf(y);
        }
      }
    }
  }
}

// ======== r20: ring-4 GEMM, 64x128 / 256thr / 48KB LDS -> 3 blocks/CU ========
// Deep prefetch (3 tiles ahead, counted vmcnt) combined with TLP — the one
// untested combination. Ledger (PL=3, proven r6-r8): prologue stages tiles
// 0-2 (9 loads), vmcnt(6) certifies tile 0. Steady tile kt: stage kt+3
// (9 in flight), vmcnt(6) drains exactly tile kt+1. Tail peel 3/0/none.
// Staging targets buf (kt+3)&3=(kt-1)&3 whose readers passed tile kt-1's
// closing barrier -> single barrier per tile is race-free. Swizzle key
// (row>>1)&3 invariant under +64-row staging offset (proven scs carries over).
// MODE 1: bf16 out = f2bf(resid_f32+v+b) [proj]; MODE 3: fp32 out [FF2].
template<int MODE>
__global__ __launch_bounds__(256) void gemm_r4(
    const u16* __restrict__ A, const u16* __restrict__ Bt,
    int M, int N, int K,
    const float* __restrict__ bias0, const void* __restrict__ resid,
    void* __restrict__ o0)
{
  constexpr int BMT = 64, BNT = 128;
  constexpr int ABUF = BMT*32, BBUF = BNT*32;   // u16 per ring buffer
  __shared__ alignas(16) u16 Ab[4][ABUF];       // 16 KB
  __shared__ alignas(16) u16 Bb[4][BBUF];       // 32 KB

  const int tid = threadIdx.x;
  const int wid = tid>>6, lane = tid&63, lr = lane&15, lg = lane>>4;
  const int wr = wid>>1, wc = wid&1;            // 2x2 wave grid, wave tile 32x64

  const int gx = gridDim.x;
  const int gy = gridDim.y;
  const int nwg = gx * gy;
  const int bid = blockIdx.x + blockIdx.y*gx;
  const int wg = (bid&7)*(nwg>>3) + (bid>>3);
  const int m0 = (wg / gy) * BMT;               // A-panel-major
  const int n0 = (wg % gy) * BNT;

  const int nkt = K/32;
  const int srow = tid>>2;                                   // 0..63
  const int scs = (((tid&3) - ((srow>>1)&3)) & 3) * 8;       // inv-swizzled src chunk

  auto stageA = [&](int kt3){
    gload_lds16(A + (size_t)(m0 + srow)*K + kt3*32 + scs, &Ab[kt3&3][tid*8]);
  };
  auto stageB = [&](int kt3){
    const u16* src = Bt + (size_t)(n0 + srow)*K + kt3*32 + scs;
    gload_lds16(src,                 &Bb[kt3&3][tid*8]);
    gload_lds16(src + (size_t)64*K,  &Bb[kt3&3][2048 + tid*8]);
  };
  auto rdA = [&](int kt, int fm) -> s16x8 {
    const int row = wr*32 + fm*16 + lr;
    return *(const s16x8*)&Ab[kt&3][row*32 + (((lg + (row>>1)) & 3)<<3)];
  };
  auto rdB = [&](int kt, int fn) -> s16x8 {
    const int row = wc*64 + fn*16 + lr;
    return *(const s16x8*)&Bb[kt&3][row*32 + (((lg + (row>>1)) & 3)<<3)];
  };

  f32x4 acc[2][4];
#pragma unroll
  for (int i = 0; i < 2; i++)
#pragma unroll
    for (int j = 0; j < 4; j++) acc[i][j] = {0.f,0.f,0.f,0.f};

  // wsel: 2 steady (drain to 6), 1 drain to 3, 0 drain to 0, -1 last (none)
  auto tile = [&](int kt, bool doStage, int wsel){
    s16x8 af, bf[4];
#pragma unroll
    for (int f = 0; f < 4; ++f) bf[f] = rdB(kt, f);
    af = rdA(kt, 0);
    if (doStage){ stageA(kt+3); stageB(kt+3); }
    __builtin_amdgcn_s_setprio(1);
#pragma unroll
    for (int f = 0; f < 4; ++f)
      acc[0][f] = __builtin_amdgcn_mfma_f32_16x16x32_bf16(af, bf[f], acc[0][f], 0, 0, 0);
    __builtin_amdgcn_s_setprio(0);
    af = rdA(kt, 1);
    __builtin_amdgcn_s_setprio(1);
#pragma unroll
    for (int f = 0; f < 4; ++f)
      acc[1][f] = __builtin_amdgcn_mfma_f32_16x16x32_bf16(af, bf[f], acc[1][f], 0, 0, 0);
    __builtin_amdgcn_s_setprio(0);
    if (wsel == 2)      WAITV(6);
    else if (wsel == 1) WAITV(3);
    else if (wsel == 0) WAITV(0);
    if (wsel >= 0) __builtin_amdgcn_s_barrier();
  };

  stageA(0); stageB(0);
  stageA(1); stageB(1);
  stageA(2); stageB(2);
  WAITV(6);
  __builtin_amdgcn_s_barrier();

  for (int kt = 0; kt < nkt - 3; ++kt) tile(kt, true, 2);
  tile(nkt-3, false, 1);
  tile(nkt-2, false, 0);
  tile(nkt-1, false, -1);

  // epilogue
#pragma unroll
  for (int fm = 0; fm < 2; fm++){
    const int gmb = m0 + wr*32 + fm*16 + lg*4;
#pragma unroll
    for (int fn = 0; fn < 4; fn++){
      const int gn = n0 + wc*64 + fn*16 + lr;
#pragma unroll
      for (int i = 0; i < 4; i++){
        const int gm = gmb + i;
        float v = acc[fm][fn][i];
        if (MODE == 1){
          ((u16*)o0)[(size_t)gm * N + gn] =
              f2bf(((const float*)resid)[(size_t)gm * N + gn] + v + bias0[gn]);
        } else {
          ((float*)o0)[(size_t)gm * N + gn] =
              bf2f(((const u16*)resid)[(size_t)gm * N + gn]) + v + bias0[gn];
        }
      }
    }
  }
}

// ---------------- flash attention (round-13, frozen) ----------------
__global__ __launch_bounds__(256) void attn_kernel(
    const u16* __restrict__ Qb, const u16* __restrict__ Kb, const u16* __restrict__ VT,
    u16* __restrict__ attnC)
{
  const int bid = blockIdx.x;
  const int bh = bid & 127, qt = bid >> 7;
  const int b = bh >> 4, h = bh & 15;
  const int tid = threadIdx.x, w = tid >> 6, lane = tid & 63;
  const int lr = lane & 15, lg = lane >> 4;
  const int q0 = qt * 128 + w * 32;

  __shared__ alignas(16) u16 Kl[2][64*64];
  __shared__ alignas(16) u16 Vl[2][64*64];
  __shared__ alignas(16) u16 Pl[4][32][72];

  const int srow = tid >> 3, scg = tid & 7;
  const u16* kbase = Kb + (size_t)(b * NSEQ) * D_EMB + h * HS;
  const u16* vbase = VT + ((size_t)(b * NH + h)) * HS * NSEQ;

  auto stage = [&](int buf, int kt){
    const int tk = kt * 64;
#pragma unroll
    for (int p = 0; p < 2; ++p){
      const int row = srow + p * 32;
      const int sc = scg ^ (row & 7);
      gload_lds16(kbase + (size_t)(tk + row) * D_EMB + sc * 8, &Kl[buf][(p * 256 + tid) * 8]);
      gload_lds16(vbase + (size_t)row * NSEQ + tk + sc * 8,    &Vl[buf][(p * 256 + tid) * 8]);
    }
  };

  s16x8 aq[2][2];
#pragma unroll
  for (int rb = 0; rb < 2; rb++)
#pragma unroll
    for (int kh = 0; kh < 2; kh++)
      aq[rb][kh] = *(const s16x8*)(Qb + (size_t)(b * NSEQ + q0 + rb * 16 + lr) * D_EMB
                                   + h * HS + kh * 32 + lg * 8);

  float m_i[2][4], l_i[2][4];
  f32x4 zero = {0.f, 0.f, 0.f, 0.f};
  f32x4 ao[2][4];
#pragma unroll
  for (int rb = 0; rb < 2; rb++)
#pragma unroll
    for (int i = 0; i < 4; i++){ m_i[rb][i] = -1e30f; l_i[rb][i] = 0.f; ao[rb][i] = zero; }

  const int rsw = lr & 7;

  stage(0, 0);
  for (int kt = 0; kt < NSEQ / 64; ++kt){
    __syncthreads();
    if (kt + 1 < NSEQ / 64) stage((kt + 1) & 1, kt + 1);
    const int cur = kt & 1;

    f32x4 sv[2][4];
#pragma unroll
    for (int rb = 0; rb < 2; rb++)
#pragma unroll
      for (int fn = 0; fn < 4; fn++) sv[rb][fn] = zero;
#pragma unroll
    for (int fn = 0; fn < 4; fn++){
      const int krow = fn * 16 + lr;
#pragma unroll
      for (int kh = 0; kh < 2; kh++){
        const int chunk = (kh * 4 + lg) ^ rsw;
        s16x8 kf = *(const s16x8*)&Kl[cur][krow * 64 + chunk * 8];
        sv[0][fn] = __builtin_amdgcn_mfma_f32_16x16x32_bf16(aq[0][kh], kf, sv[0][fn], 0, 0, 0);
        sv[1][fn] = __builtin_amdgcn_mfma_f32_16x16x32_bf16(aq[1][kh], kf, sv[1][fn], 0, 0, 0);
      }
    }

#pragma unroll
    for (int rb = 0; rb < 2; rb++){
      float p[4][4];
#pragma unroll
      for (int i = 0; i < 4; i++){
        float s0 = sv[rb][0][i], s1 = sv[rb][1][i];
        float s2 = sv[rb][2][i], s3 = sv[rb][3][i];
        float lmax = fmaxf(fmaxf(s0, s1), fmaxf(s2, s3));     // per-lane only
        if (__any(lmax > m_i[rb][i] + 8.0f)){                 // rare, wave-uniform
          float rmax = lmax;
#pragma unroll
          for (int mm = 8; mm > 0; mm >>= 1) rmax = fmaxf(rmax, __shfl_xor(rmax, mm));
          float mnew = fmaxf(m_i[rb][i], rmax);
          float fac = exp2f(m_i[rb][i] - mnew);
          l_i[rb][i] *= fac;
#pragma unroll
          for (int fn = 0; fn < 4; fn++) ao[rb][fn][i] *= fac;
          m_i[rb][i] = mnew;
        }
        const float m = m_i[rb][i];
        float p0 = exp2f(s0 - m), p1 = exp2f(s1 - m);
        float p2 = exp2f(s2 - m), p3 = exp2f(s3 - m);
        p[0][i] = p0; p[1][i] = p1; p[2][i] = p2; p[3][i] = p3;
        l_i[rb][i] += (p0 + p1) + (p2 + p3);        // per-lane partial sum
      }
#pragma unroll
      for (int fn = 0; fn < 4; fn++)
#pragma unroll
        for (int i = 0; i < 4; i++)
          Pl[w][rb * 16 + lg * 4 + i][fn * 16 + lr] = bft(p[fn][i]);
    }

    s16x8 vf[4][2];
#pragma unroll
    for (int fn = 0; fn < 4; fn++){
      const int vrow = fn * 16 + lr;
#pragma unroll
      for (int kh = 0; kh < 2; kh++){
        const int chunk = (kh * 4 + lg) ^ rsw;
        vf[fn][kh] = *(const s16x8*)&Vl[cur][vrow * 64 + chunk * 8];
      }
    }
#pragma unroll
    for (int rb = 0; rb < 2; rb++){
      s16x8 pa0 = *(const s16x8*)&Pl[w][rb * 16 + lr][lg * 8];
      s16x8 pa1 = *(const s16x8*)&Pl[w][rb * 16 + lr][32 + lg * 8];
#pragma unroll
      for (int fn = 0; fn < 4; fn++){
        ao[rb][fn] = __builtin_amdgcn_mfma_f32_16x16x32_bf16(pa0, vf[fn][0], ao[rb][fn], 0, 0, 0);
        ao[rb][fn] = __builtin_amdgcn_mfma_f32_16x16x32_bf16(pa1, vf[fn][1], ao[rb][fn], 0, 0, 0);
      }
    }
  }

#pragma unroll
  for (int rb = 0; rb < 2; rb++)
#pragma unroll
    for (int i = 0; i < 4; i++)
#pragma unroll
      for (int mm = 8; mm > 0; mm >>= 1) l_i[rb][i] += __shfl_xor(l_i[rb][i], mm);

#pragma unroll
  for (int rb = 0; rb < 2; rb++)
#pragma unroll
    for (int fn = 0; fn < 4; fn++)
#pragma unroll
      for (int i = 0; i < 4; i++){
        float v = ao[rb][fn][i] / l_i[rb][i];
        attnC[(size_t)(b * NSEQ + q0 + rb * 16 + lg * 4 + i) * D_EMB + h * HS + fn * 16 + lr] = f2bf(v);
      }
}

// ---------------- host ----------------
extern "C" void kernel_launch(void* const* d_in, const int* in_sizes, int n_in,
                              void* d_out, int out_size, void* d_ws, size_t ws_size,
                              hipStream_t stream)
{
  const float* x    = (const float*)d_in[0];
  const float* Wq   = (const float*)d_in[1];
  const float* bq   = (const float*)d_in[2];
  const float* Wk   = (const float*)d_in[3];
  const float* bk   = (const float*)d_in[4];
  const float* Wv   = (const float*)d_in[5];
  const float* bv   = (const float*)d_in[6];
  const float* Wp   = (const float*)d_in[7];
  const float* bp   = (const float*)d_in[8];
  const float* W1   = (const float*)d_in[9];
  const float* b1   = (const float*)d_in[10];
  const float* W2   = (const float*)d_in[11];
  const float* b2   = (const float*)d_in[12];
  const float* ln1g = (const float*)d_in[13];
  const float* ln1b = (const float*)d_in[14];
  const float* ln2g = (const float*)d_in[15];
  const float* ln2b = (const float*)d_in[16];
  float* out = (float*)d_out;

  char* ws = (char*)d_ws;
  size_t off = 0;
  auto mk = [&](size_t bytes)->void*{ void* p = ws + off; off += (bytes + 255) & ~(size_t)255; return p; };
  u16*  h1    = (u16*) mk((size_t)MTOT * D_EMB * 2);
  u16*  Qb    = (u16*) mk((size_t)MTOT * D_EMB * 2);
  u16*  Kb    = (u16*) mk((size_t)MTOT * D_EMB * 2);
  u16*  VTb   = (u16*) mk((size_t)MTOT * D_EMB * 2);
  u16*  attnC = (u16*) mk((size_t)MTOT * D_EMB * 2);
  u16*  x1b   = (u16*) mk((size_t)MTOT * D_EMB * 2);   // bf16 residual stream
  u16*  h2    = (u16*) mk((size_t)MTOT * D_EMB * 2);
  u16*  ffb   = (u16*) mk((size_t)MTOT * DFF * 2);
  u16*  WqkvT = (u16*) mk((size_t)3 * D_EMB * D_EMB * 2);
  u16*  WpT   = (u16*) mk((size_t)D_EMB * D_EMB * 2);
  u16*  W1T   = (u16*) mk((size_t)D_EMB * DFF * 2);
  u16*  W2T   = (u16*) mk((size_t)D_EMB * DFF * 2);

  dim3 tb(32, 8, 1);
  transpose_cvt_qkv<<<dim3(HS/32, D_EMB/32, 3*NH), tb, 0, stream>>>(Wq, Wk, Wv, WqkvT);
  transpose_cvt<<<dim3(D_EMB/32, D_EMB/32, 1), tb, 0, stream>>>(Wp, WpT,  D_EMB, D_EMB, 0, 0);
  transpose_cvt<<<dim3(DFF/32,  D_EMB/32, 1), tb, 0, stream>>>(W1, W1T,  D_EMB, DFF,   0, 0);
  transpose_cvt<<<dim3(D_EMB/32, DFF/32,  1), tb, 0, stream>>>(W2, W2T,  DFF,   D_EMB, 0, 0);

  ln_kernel<false><<<MTOT, 256, 0, stream>>>(x, ln1g, ln1b, h1);

  // QKV: 128x256 / 512 thr (r15 best) — grid 64x12=768
  gemm2ph<0,128,256,512><<<dim3(MTOT/128, 3*D_EMB/256), 512, 0, stream>>>(
      h1, WqkvT, MTOT, 3*D_EMB, D_EMB, bq, bk, bv, nullptr, Qb, Kb, VTb);

  attn_kernel<<<NB*NH*(NSEQ/128), 256, 0, stream>>>(Qb, Kb, VTb, attnC);

  // proj: r20 ring-4 deep-prefetch + 3 blocks/CU; fp32 resid -> bf16 x1
  gemm_r4<1><<<dim3(MTOT/64, D_EMB/128), 256, 0, stream>>>(
      attnC, WpT, MTOT, D_EMB, D_EMB, bp, x, x1b);

  ln_kernel<true><<<MTOT, 256, 0, stream>>>(x1b, ln2g, ln2b, h2);

  // FF1: 128x256 / 512 thr (r15 best) — grid 64x16=1024
  gemm2ph<2,128,256,512><<<dim3(MTOT/128, DFF/256), 512, 0, stream>>>(
      h2, W1T, MTOT, DFF, D_EMB, b1, nullptr, nullptr, nullptr, ffb, nullptr, nullptr);

  // FF2: r20 ring-4; bf16 resid -> fp32 out
  gemm_r4<3><<<dim3(MTOT/64, D_EMB/128), 256, 0, stream>>>(
      ffb, W2T, MTOT, D_EMB, DFF, b2, x1b, out);
}

// Round 21
// 421.864 us; speedup vs baseline: 1.0891x; 1.0891x over previous
//
#include <hip/hip_runtime.h>
#include <cstdint>
#include <cstddef>

typedef unsigned short u16;
typedef __attribute__((ext_vector_type(4))) float f32x4;
typedef __attribute__((ext_vector_type(8))) short s16x8;

#define D_EMB 1024
#define NSEQ 1024
#define NB 8
#define NH 16
#define HS 64
#define DFF 4096
#define MTOT (NB*NSEQ)

__device__ __forceinline__ u16 f2bf(float f){
  unsigned u = __float_as_uint(f);
  u += 0x7FFFu + ((u >> 16) & 1u);     // round-to-nearest-even
  return (u16)(u >> 16);
}
// truncating convert (P-tile only: P>0, <=1 ULP bias cancels in softmax ratio)
__device__ __forceinline__ u16 bft(float f){ return (u16)(__float_as_uint(f) >> 16); }
__device__ __forceinline__ float bf2f(u16 v){ return __uint_as_float(((unsigned)v) << 16); }

__device__ __forceinline__ void gload_lds16(const void* g, void* l){
  __builtin_amdgcn_global_load_lds((const __attribute__((address_space(1))) void*)g,
                                   (__attribute__((address_space(3))) void*)l, 16, 0, 0);
}

// ---------------- tiled transpose + fp32->bf16 convert ----------------
__global__ void transpose_cvt(const float* __restrict__ in, u16* __restrict__ out,
                              int R, int C, size_t inStride, size_t outStride){
  __shared__ float t[32][33];
  const float* ip = in + (size_t)blockIdx.z * inStride;
  u16* op = out + (size_t)blockIdx.z * outStride;
  int c0 = blockIdx.x * 32, r0 = blockIdx.y * 32;
  int tx = threadIdx.x, ty = threadIdx.y;
#pragma unroll
  for (int j = 0; j < 32; j += 8)
    t[ty + j][tx] = ip[(size_t)(r0 + ty + j) * C + (c0 + tx)];
  __syncthreads();
#pragma unroll
  for (int j = 0; j < 32; j += 8)
    op[(size_t)(c0 + ty + j) * R + (r0 + tx)] = f2bf(t[tx][ty + j]);
}

// merged QKV weight transpose: z in [0,48), weight = z/16, head = z%16
__global__ void transpose_cvt_qkv(const float* __restrict__ Wq,
                                  const float* __restrict__ Wk,
                                  const float* __restrict__ Wv,
                                  u16* __restrict__ out){
  __shared__ float t[32][33];
  const int z = blockIdx.z, wsel = z >> 4, h = z & 15;
  const float* w = (wsel == 0) ? Wq : (wsel == 1) ? Wk : Wv;
  const float* ip = w + (size_t)h * D_EMB * HS;
  u16* op = out + (size_t)wsel * D_EMB * D_EMB + (size_t)h * HS * D_EMB;
  int c0 = blockIdx.x * 32, r0 = blockIdx.y * 32;
  int tx = threadIdx.x, ty = threadIdx.y;
#pragma unroll
  for (int j = 0; j < 32; j += 8)
    t[ty + j][tx] = ip[(size_t)(r0 + ty + j) * HS + (c0 + tx)];
  __syncthreads();
#pragma unroll
  for (int j = 0; j < 32; j += 8)
    op[(size_t)(c0 + ty + j) * D_EMB + (r0 + tx)] = f2bf(t[tx][ty + j]);
}

// ---------------- LayerNorm (fp32 OR bf16 in, bf16 out) ----------------
template<bool BF16IN>
__global__ __launch_bounds__(256) void ln_kernel(const void* __restrict__ xin,
    const float* __restrict__ g, const float* __restrict__ bb, u16* __restrict__ out){
  int row = blockIdx.x;
  int c = threadIdx.x * 4;
  float v0, v1, v2, v3;
  if (BF16IN){
    const u16* xr = (const u16*)xin + (size_t)row * D_EMB;
    ushort4 u = *(const ushort4*)(xr + c);
    v0 = bf2f(u.x); v1 = bf2f(u.y); v2 = bf2f(u.z); v3 = bf2f(u.w);
  } else {
    const float* xr = (const float*)xin + (size_t)row * D_EMB;
    f32x4 v = *(const f32x4*)(xr + c);
    v0 = v[0]; v1 = v[1]; v2 = v[2]; v3 = v[3];
  }
  float s1 = v0 + v1 + v2 + v3;
  float s2 = v0*v0 + v1*v1 + v2*v2 + v3*v3;
#pragma unroll
  for (int m = 32; m > 0; m >>= 1){ s1 += __shfl_xor(s1, m); s2 += __shfl_xor(s2, m); }
  __shared__ float ps1[4], ps2[4];
  int w = threadIdx.x >> 6;
  if ((threadIdx.x & 63) == 0){ ps1[w] = s1; ps2[w] = s2; }
  __syncthreads();
  s1 = ps1[0] + ps1[1] + ps1[2] + ps1[3];
  s2 = ps2[0] + ps2[1] + ps2[2] + ps2[3];
  float mu = s1 * (1.f / D_EMB);
  float var = s2 * (1.f / D_EMB) - mu * mu;
  float rs = rsqrtf(var + 1e-5f);
  ushort4 o;
  o.x = f2bf((v0-mu)*rs*g[c+0] + bb[c+0]);
  o.y = f2bf((v1-mu)*rs*g[c+1] + bb[c+1]);
  o.z = f2bf((v2-mu)*rs*g[c+2] + bb[c+2]);
  o.w = f2bf((v3-mu)*rs*g[c+3] + bb[c+3]);
  *(ushort4*)(out + (size_t)row * D_EMB + c) = o;
}

// ======== 2-phase GEMM template, A-panel-major block order (r15/r19 best) ========
// C = A[M,K] * Bt[N,K]^T, bf16 in, fp32 acc. BK=32, double-buffered LDS,
// __syncthreads-scheduled (compiler counted waits + inter-block TLP, m114).
// A-panel-major: consecutive wg walk N so blocks sharing an A panel run
// back-to-back on one XCD. Swizzle (0-conflict, r7): read chunk
// ch=(lg+(row>>1))&3, inverse-permuted global src chunk, linear LDS.
// MODE 0: QKV (Q scaled 0.125*log2e); MODE 1: bf16 out = f2bf(resid_f32+v+b);
// MODE 2: ff1 leakyrelu bf16; MODE 3: fp32 out = bf2f(resid_bf16)+v+b.
template<int MODE, int BMT, int BNT, int NTHR>
__global__ __launch_bounds__(NTHR) void gemm2ph(
    const u16* __restrict__ A, const u16* __restrict__ Bt,
    int M, int N, int K,
    const float* __restrict__ bias0, const float* __restrict__ bias1,
    const float* __restrict__ bias2, const void* __restrict__ resid,
    void* __restrict__ o0, void* __restrict__ o1, void* __restrict__ o2)
{
  constexpr int NWAVE = NTHR/64;
  constexpr int WCN = BNT/64, WRN = NWAVE/WCN;
  constexpr int WROWS = BMT/WRN;                 // rows per wave
  constexpr int RF = WROWS/16;                   // row fragments per wave
  static_assert(RF*16*WRN == BMT, "wave tiling must cover BMT");
  constexpr int RPP = NTHR/4;                    // rows staged per pass
  constexpr int ALD = (BMT*32)/(NTHR*8);         // 16B loads/thread for A
  constexpr int BLD = (BNT*32)/(NTHR*8);
  __shared__ alignas(16) u16 Al[2][BMT*32];
  __shared__ alignas(16) u16 Bl[2][BNT*32];

  const int tid = threadIdx.x;
  const int wid = tid>>6, lane = tid&63, lr = lane&15, lg = lane>>4;
  const int wr = wid/WCN, wc = wid%WCN;

  // XCD swizzle (all grids divisible by 8) + A-panel-major (n inner)
  const int gx = gridDim.x;
  const int gy = gridDim.y;
  const int nwg = gx * gy;
  const int bid = blockIdx.x + blockIdx.y*gx;
  const int wg = (bid&7)*(nwg>>3) + (bid>>3);
  const int m0 = (wg / gy) * BMT;    // consecutive wg share m0 (A panel)
  const int n0 = (wg % gy) * BNT;

  const int srow = tid>>2;                                   // staging row
  const int scs = (((tid&3) - ((srow>>1)&3)) & 3) * 8;       // inv-swizzled src chunk

  auto stage = [&](int buf, int kt){
    const u16* asrc = A + (size_t)(m0 + srow)*K + kt*32 + scs;
#pragma unroll
    for (int r = 0; r < ALD; ++r)
      gload_lds16(asrc + (size_t)(r*RPP)*K, &Al[buf][r*(NTHR*8) + tid*8]);
    const u16* bsrc = Bt + (size_t)(n0 + srow)*K + kt*32 + scs;
#pragma unroll
    for (int r = 0; r < BLD; ++r)
      gload_lds16(bsrc + (size_t)(r*RPP)*K, &Bl[buf][r*(NTHR*8) + tid*8]);
  };

  f32x4 acc[RF][4];
#pragma unroll
  for (int i = 0; i < RF; i++)
#pragma unroll
    for (int j = 0; j < 4; j++) acc[i][j] = {0.f,0.f,0.f,0.f};

  const int nk = K/32;
  stage(0, 0);
  for (int kt = 0; kt < nk; ++kt){
    __syncthreads();                   // drains vmcnt: stage(kt) visible
    if (kt + 1 < nk) stage((kt+1)&1, kt+1);
    const int buf = kt & 1;
    s16x8 af[RF], bf[4];
#pragma unroll
    for (int i = 0; i < RF; i++){
      const int ar = wr*WROWS + i*16 + lr;
      af[i] = *(const s16x8*)&Al[buf][ar*32 + (((lg + (ar>>1)) & 3)<<3)];
    }
#pragma unroll
    for (int j = 0; j < 4; j++){
      const int br = wc*64 + j*16 + lr;
      bf[j] = *(const s16x8*)&Bl[buf][br*32 + (((lg + (br>>1)) & 3)<<3)];
    }
#pragma unroll
    for (int i = 0; i < RF; i++)
#pragma unroll
      for (int j = 0; j < 4; j++)
        acc[i][j] = __builtin_amdgcn_mfma_f32_16x16x32_bf16(af[i], bf[j], acc[i][j], 0, 0, 0);
  }

  // epilogue: lane holds C[row=lg*4+i][col=lr] per 16x16 fragment
#pragma unroll
  for (int fm = 0; fm < RF; fm++){
    const int gmb = m0 + wr*WROWS + fm*16 + lg*4;
#pragma unroll
    for (int fn = 0; fn < 4; fn++){
      const int gn = n0 + wc*64 + fn*16 + lr;
#pragma unroll
      for (int i = 0; i < 4; i++){
        const int gm = gmb + i;
        float v = acc[fm][fn][i];
        if (MODE == 0){
          const int cls = gn >> 10, nn = gn & 1023;
          if (cls == 0)      ((u16*)o0)[(size_t)gm * D_EMB + nn] = f2bf((v + bias0[nn]) * 0.18033688f); // 0.125*log2e
          else if (cls == 1) ((u16*)o1)[(size_t)gm * D_EMB + nn] = f2bf(v + bias1[nn]);
          else {
            const int hh = nn >> 6, ss = nn & 63, bb = gm >> 10, tt = gm & 1023;
            ((u16*)o2)[(((size_t)(bb * NH + hh)) * HS + ss) * NSEQ + tt] = f2bf(v + bias2[nn]);
          }
        } else if (MODE == 1){
          // proj: fp32 resid (original x) -> bf16 x1
          ((u16*)o0)[(size_t)gm * N + gn] =
              f2bf(((const float*)resid)[(size_t)gm * N + gn] + v + bias0[gn]);
        } else if (MODE == 3){
          // FF2: bf16 resid (x1) -> fp32 out
          ((float*)o0)[(size_t)gm * N + gn] =
              bf2f(((const u16*)resid)[(size_t)gm * N + gn]) + v + bias0[gn];
        } else {
          float y = v + bias0[gn];
          y = y > 0.f ? y : 0.01f * y;
          ((u16*)o0)[(size_t)gm * N + gn] = f2bf(y);
        }
      }
    }
  }
}

// ---------------- flash attention (round-13, frozen) ----------------
__global__ __launch_bounds__(256) void attn_kernel(
    const u16* __restrict__ Qb, const u16* __restrict__ Kb, const u16* __restrict__ VT,
    u16* __restrict__ attnC)
{
  const int bid = blockIdx.x;
  const int bh = bid & 127, qt = bid >> 7;
  const int b = bh >> 4, h = bh & 15;
  const int tid = threadIdx.x, w = tid >> 6, lane = tid & 63;
  const int lr = lane & 15, lg = lane >> 4;
  const int q0 = qt * 128 + w * 32;

  __shared__ alignas(16) u16 Kl[2][64*64];
  __shared__ alignas(16) u16 Vl[2][64*64];
  __shared__ alignas(16) u16 Pl[4][32][72];

  const int srow = tid >> 3, scg = tid & 7;
  const u16* kbase = Kb + (size_t)(b * NSEQ) * D_EMB + h * HS;
  const u16* vbase = VT + ((size_t)(b * NH + h)) * HS * NSEQ;

  auto stage = [&](int buf, int kt){
    const int tk = kt * 64;
#pragma unroll
    for (int p = 0; p < 2; ++p){
      const int row = srow + p * 32;
      const int sc = scg ^ (row & 7);
      gload_lds16(kbase + (size_t)(tk + row) * D_EMB + sc * 8, &Kl[buf][(p * 256 + tid) * 8]);
      gload_lds16(vbase + (size_t)row * NSEQ + tk + sc * 8,    &Vl[buf][(p * 256 + tid) * 8]);
    }
  };

  s16x8 aq[2][2];
#pragma unroll
  for (int rb = 0; rb < 2; rb++)
#pragma unroll
    for (int kh = 0; kh < 2; kh++)
      aq[rb][kh] = *(const s16x8*)(Qb + (size_t)(b * NSEQ + q0 + rb * 16 + lr) * D_EMB
                                   + h * HS + kh * 32 + lg * 8);

  float m_i[2][4], l_i[2][4];
  f32x4 zero = {0.f, 0.f, 0.f, 0.f};
  f32x4 ao[2][4];
#pragma unroll
  for (int rb = 0; rb < 2; rb++)
#pragma unroll
    for (int i = 0; i < 4; i++){ m_i[rb][i] = -1e30f; l_i[rb][i] = 0.f; ao[rb][i] = zero; }

  const int rsw = lr & 7;

  stage(0, 0);
  for (int kt = 0; kt < NSEQ / 64; ++kt){
    __syncthreads();
    if (kt + 1 < NSEQ / 64) stage((kt + 1) & 1, kt + 1);
    const int cur = kt & 1;

    f32x4 sv[2][4];
#pragma unroll
    for (int rb = 0; rb < 2; rb++)
#pragma unroll
      for (int fn = 0; fn < 4; fn++) sv[rb][fn] = zero;
#pragma unroll
    for (int fn = 0; fn < 4; fn++){
      const int krow = fn * 16 + lr;
#pragma unroll
      for (int kh = 0; kh < 2; kh++){
        const int chunk = (kh * 4 + lg) ^ rsw;
        s16x8 kf = *(const s16x8*)&Kl[cur][krow * 64 + chunk * 8];
        sv[0][fn] = __builtin_amdgcn_mfma_f32_16x16x32_bf16(aq[0][kh], kf, sv[0][fn], 0, 0, 0);
        sv[1][fn] = __builtin_amdgcn_mfma_f32_16x16x32_bf16(aq[1][kh], kf, sv[1][fn], 0, 0, 0);
      }
    }

#pragma unroll
    for (int rb = 0; rb < 2; rb++){
      float p[4][4];
#pragma unroll
      for (int i = 0; i < 4; i++){
        float s0 = sv[rb][0][i], s1 = sv[rb][1][i];
        float s2 = sv[rb][2][i], s3 = sv[rb][3][i];
        float lmax = fmaxf(fmaxf(s0, s1), fmaxf(s2, s3));     // per-lane only
        if (__any(lmax > m_i[rb][i] + 8.0f)){                 // rare, wave-uniform
          float rmax = lmax;
#pragma unroll
          for (int mm = 8; mm > 0; mm >>= 1) rmax = fmaxf(rmax, __shfl_xor(rmax, mm));
          float mnew = fmaxf(m_i[rb][i], rmax);
          float fac = exp2f(m_i[rb][i] - mnew);
          l_i[rb][i] *= fac;
#pragma unroll
          for (int fn = 0; fn < 4; fn++) ao[rb][fn][i] *= fac;
          m_i[rb][i] = mnew;
        }
        const float m = m_i[rb][i];
        float p0 = exp2f(s0 - m), p1 = exp2f(s1 - m);
        float p2 = exp2f(s2 - m), p3 = exp2f(s3 - m);
        p[0][i] = p0; p[1][i] = p1; p[2][i] = p2; p[3][i] = p3;
        l_i[rb][i] += (p0 + p1) + (p2 + p3);        // per-lane partial sum
      }
#pragma unroll
      for (int fn = 0; fn < 4; fn++)
#pragma unroll
        for (int i = 0; i < 4; i++)
          Pl[w][rb * 16 + lg * 4 + i][fn * 16 + lr] = bft(p[fn][i]);
    }

    s16x8 vf[4][2];
#pragma unroll
    for (int fn = 0; fn < 4; fn++){
      const int vrow = fn * 16 + lr;
#pragma unroll
      for (int kh = 0; kh < 2; kh++){
        const int chunk = (kh * 4 + lg) ^ rsw;
        vf[fn][kh] = *(const s16x8*)&Vl[cur][vrow * 64 + chunk * 8];
      }
    }
#pragma unroll
    for (int rb = 0; rb < 2; rb++){
      s16x8 pa0 = *(const s16x8*)&Pl[w][rb * 16 + lr][lg * 8];
      s16x8 pa1 = *(const s16x8*)&Pl[w][rb * 16 + lr][32 + lg * 8];
#pragma unroll
      for (int fn = 0; fn < 4; fn++){
        ao[rb][fn] = __builtin_amdgcn_mfma_f32_16x16x32_bf16(pa0, vf[fn][0], ao[rb][fn], 0, 0, 0);
        ao[rb][fn] = __builtin_amdgcn_mfma_f32_16x16x32_bf16(pa1, vf[fn][1], ao[rb][fn], 0, 0, 0);
      }
    }
  }

#pragma unroll
  for (int rb = 0; rb < 2; rb++)
#pragma unroll
    for (int i = 0; i < 4; i++)
#pragma unroll
      for (int mm = 8; mm > 0; mm >>= 1) l_i[rb][i] += __shfl_xor(l_i[rb][i], mm);

#pragma unroll
  for (int rb = 0; rb < 2; rb++)
#pragma unroll
    for (int fn = 0; fn < 4; fn++)
#pragma unroll
      for (int i = 0; i < 4; i++){
        float v = ao[rb][fn][i] / l_i[rb][i];
        attnC[(size_t)(b * NSEQ + q0 + rb * 16 + lg * 4 + i) * D_EMB + h * HS + fn * 16 + lr] = f2bf(v);
      }
}

// ---------------- host ----------------
extern "C" void kernel_launch(void* const* d_in, const int* in_sizes, int n_in,
                              void* d_out, int out_size, void* d_ws, size_t ws_size,
                              hipStream_t stream)
{
  const float* x    = (const float*)d_in[0];
  const float* Wq   = (const float*)d_in[1];
  const float* bq   = (const float*)d_in[2];
  const float* Wk   = (const float*)d_in[3];
  const float* bk   = (const float*)d_in[4];
  const float* Wv   = (const float*)d_in[5];
  const float* bv   = (const float*)d_in[6];
  const float* Wp   = (const float*)d_in[7];
  const float* bp   = (const float*)d_in[8];
  const float* W1   = (const float*)d_in[9];
  const float* b1   = (const float*)d_in[10];
  const float* W2   = (const float*)d_in[11];
  const float* b2   = (const float*)d_in[12];
  const float* ln1g = (const float*)d_in[13];
  const float* ln1b = (const float*)d_in[14];
  const float* ln2g = (const float*)d_in[15];
  const float* ln2b = (const float*)d_in[16];
  float* out = (float*)d_out;

  char* ws = (char*)d_ws;
  size_t off = 0;
  auto mk = [&](size_t bytes)->void*{ void* p = ws + off; off += (bytes + 255) & ~(size_t)255; return p; };
  u16*  h1    = (u16*) mk((size_t)MTOT * D_EMB * 2);
  u16*  Qb    = (u16*) mk((size_t)MTOT * D_EMB * 2);
  u16*  Kb    = (u16*) mk((size_t)MTOT * D_EMB * 2);
  u16*  VTb   = (u16*) mk((size_t)MTOT * D_EMB * 2);
  u16*  attnC = (u16*) mk((size_t)MTOT * D_EMB * 2);
  u16*  x1b   = (u16*) mk((size_t)MTOT * D_EMB * 2);   // bf16 residual stream
  u16*  h2    = (u16*) mk((size_t)MTOT * D_EMB * 2);
  u16*  ffb   = (u16*) mk((size_t)MTOT * DFF * 2);
  u16*  WqkvT = (u16*) mk((size_t)3 * D_EMB * D_EMB * 2);
  u16*  WpT   = (u16*) mk((size_t)D_EMB * D_EMB * 2);
  u16*  W1T   = (u16*) mk((size_t)D_EMB * DFF * 2);
  u16*  W2T   = (u16*) mk((size_t)D_EMB * DFF * 2);

  dim3 tb(32, 8, 1);
  // merged per-head QKV weight transpose (3 launches -> 1)
  transpose_cvt_qkv<<<dim3(HS/32, D_EMB/32, 3*NH), tb, 0, stream>>>(Wq, Wk, Wv, WqkvT);
  transpose_cvt<<<dim3(D_EMB/32, D_EMB/32, 1), tb, 0, stream>>>(Wp, WpT,  D_EMB, D_EMB, 0, 0);
  transpose_cvt<<<dim3(DFF/32,  D_EMB/32, 1), tb, 0, stream>>>(W1, W1T,  D_EMB, DFF,   0, 0);
  transpose_cvt<<<dim3(D_EMB/32, DFF/32,  1), tb, 0, stream>>>(W2, W2T,  DFF,   D_EMB, 0, 0);

  ln_kernel<false><<<MTOT, 256, 0, stream>>>(x, ln1g, ln1b, h1);

  // QKV: 128x256 / 512 thr (r15 best) — grid 64x12=768
  gemm2ph<0,128,256,512><<<dim3(MTOT/128, 3*D_EMB/256), 512, 0, stream>>>(
      h1, WqkvT, MTOT, 3*D_EMB, D_EMB, bq, bk, bv, nullptr, Qb, Kb, VTb);

  attn_kernel<<<NB*NH*(NSEQ/128), 256, 0, stream>>>(Qb, Kb, VTb, attnC);

  // proj: fp32 resid (x) -> bf16 x1; 64x128, grid 128x8=1024
  gemm2ph<1,64,128,256><<<dim3(MTOT/64, D_EMB/128), 256, 0, stream>>>(
      attnC, WpT, MTOT, D_EMB, D_EMB, bp, nullptr, nullptr, x, x1b, nullptr, nullptr);

  ln_kernel<true><<<MTOT, 256, 0, stream>>>(x1b, ln2g, ln2b, h2);

  // FF1: 128x256 / 512 thr (r15 best) — grid 64x16=1024
  gemm2ph<2,128,256,512><<<dim3(MTOT/128, DFF/256), 512, 0, stream>>>(
      h2, W1T, MTOT, DFF, D_EMB, b1, nullptr, nullptr, nullptr, ffb, nullptr, nullptr);

  // FF2: bf16 resid (x1) -> fp32 out; 64x128, grid 128x8=1024
  gemm2ph<3,64,128,256><<<dim3(MTOT/64, D_EMB/128), 256, 0, stream>>>(
      ffb, W2T, MTOT, D_EMB, DFF, b2, nullptr, nullptr, x1b, out, nullptr, nullptr);
}